// Round 14
// baseline (199.212 us; speedup 1.0000x reference)
//
#include <hip/hip_runtime.h>

#define CC 128
#define SB 16384   // T*H*W

typedef _Float16 half2_t __attribute__((ext_vector_type(2)));
typedef _Float16 half4_t __attribute__((ext_vector_type(4)));
typedef _Float16 half8_t __attribute__((ext_vector_type(8)));
typedef float    f32x4  __attribute__((ext_vector_type(4)));

// ---- workspace map ----
#define WH_OFF   0u         // 3*64*128 fp16 weights [set][m][k]
#define BIAS_OFF 49152u     // 192 f32
#define CM_OFF   50176u     // 8*1024 f32 Cm
#define SUME_OFF 82944u     // 512 f32 (zeroed by k0, atomicAdd by kC)
#define AB_OFF   86016u     // 8*4096 f32 AB accumulators (zeroed by k0, atomicAdd by kC)
#define PT_OFF   262144u    // P_t = e*V fp16 [b][s][n0..63], dense 128B rows (16.8MB)
#define VT_OFF   33816576u  // 8*16384*64 fp16 V [s][n]

// ---------------------------------------------------------------- k0: setup
// R10-proven: MLP weight reads vectorized (float4) -- was the G13 violation
// (64 scalar fp32 loads/output at 256B lane stride); -10.3us total.
__global__ void k0_setup(const float* __restrict__ cond,
                         const float* __restrict__ W_phi, const float* __restrict__ b_phi,
                         const float* __restrict__ W_theta, const float* __restrict__ b_theta,
                         const float* __restrict__ W_rho, const float* __restrict__ b_rho,
                         const float* __restrict__ W1, const float* __restrict__ b1,
                         const float* __restrict__ W2, const float* __restrict__ b2,
                         char* __restrict__ wsc) {
  __shared__ float sc[64], sh1[64], red[256];
  int t = threadIdx.x, bid = blockIdx.x;
  if (bid < 8) {
    int b = bid;
    if (t < 64) sc[t] = cond[b*64 + t];
    __syncthreads();
    if (t < 64) {
      float acc = b1[t];
      const float4* w1r = (const float4*)(W1 + t*64);
      #pragma unroll
      for (int k = 0; k < 16; ++k) {
        float4 w = w1r[k];
        acc += sc[k*4+0]*w.x + sc[k*4+1]*w.y + sc[k*4+2]*w.z + sc[k*4+3]*w.w;
      }
      sh1[t] = fmaxf(acc, 0.f);
    }
    __syncthreads();
    float ev[4]; float ps = 0.f;
    #pragma unroll
    for (int q = 0; q < 4; ++q) {
      int o = q*256 + t;
      float acc = b2[o];
      const float4* w2r = (const float4*)(W2 + o*64);
      #pragma unroll
      for (int k = 0; k < 16; ++k) {
        float4 w = w2r[k];
        acc += sh1[k*4+0]*w.x + sh1[k*4+1]*w.y + sh1[k*4+2]*w.z + sh1[k*4+3]*w.w;
      }
      ev[q] = __expf(fmaxf(acc, 0.f));
      ps += ev[q];
    }
    red[t] = ps; __syncthreads();
    for (int s = 128; s > 0; s >>= 1) { if (t < s) red[t] += red[t+s]; __syncthreads(); }
    float inv = 1.f / red[0];
    float* cm = (float*)(wsc + CM_OFF);
    #pragma unroll
    for (int q = 0; q < 4; ++q) cm[b*1024 + q*256 + t] = ev[q] * inv;
  } else {
    int r = bid - 8;
    _Float16* wh = (_Float16*)(wsc + WH_OFF);
    for (int i = r*256 + t; i < 24576; i += 2048) {
      int set = i >> 13, mk = i & 8191;
      const float* W = (set == 0) ? W_phi : (set == 1 ? W_theta : W_rho);
      wh[i] = (_Float16)W[mk];       // all W_* are [64][128] row-major already
    }
    float* ab = (float*)(wsc + AB_OFF);
    for (int i = r*256 + t; i < 32768; i += 2048) ab[i] = 0.f;
    if (r == 0 && t < 192) {
      float* bias = (float*)(wsc + BIAS_OFF);
      bias[t] = (t < 64) ? b_phi[t] : (t < 128 ? b_theta[t-64] : b_rho[t-128]);
    }
    if (r == 1) {
      float* se = (float*)(wsc + SUME_OFF);
      for (int i = t; i < 512; i += 256) se[i] = 0.f;
    }
  }
}

// ------------------------------------- kC: transpose-in-LDS + 3 convs (MFMA)
//                                          + epilogues + AB atomic accumulation
// FROZEN at R12 (54-58us, VGPR 88). Conv body = R6 codegen law (FULL
// af[4][4]+bf[2][4] preload at 128-s tile; all restructures collapsed to
// VGPR<=64 and serialized: R3/R5/R7). Tail = R12 LDS-bounced coalesced flush
// (-5us from halved store-instruction count; WRITE_SIZE unchanged -- L2
// assembles full lines regardless, the +16.8MB over ideal is the AB atomics'
// memory-side RMW traffic, structural to k2-elimination). Do NOT touch.
// ev[4][2][4] f32 MUST stay exact in regs (fp16 e-roundtrip fails attn, R2).
// Frag maps (m89/m120-verified): A[m=ln][k=q*8+j], B[k=q*8+j][n=ln], D[m=q*4+r][n=ln].
__global__ __launch_bounds__(256, 2) void kC_main(
    const float* __restrict__ x, const _Float16* __restrict__ wh,
    const float* __restrict__ bias, const float* __restrict__ cm,
    float* __restrict__ sumE, _Float16* __restrict__ vt,
    char* __restrict__ ptb,            // P region base (dense 128B rows)
    float* __restrict__ abf) {         // [8][64][64] f32 atomic accumulators
  __shared__ char smem[35328];         // union: Xh[128*138] | (A_l[64*136] + E_l[64*136])
  __shared__ float se_l[256];          // per-wave sumE partials [wv][64]
  __shared__ _Float16 Vst[128*72];     // V staging [s][n], 144B rows
  __shared__ _Float16 Pst[128*72];     // P staging [s][n], 144B rows
  _Float16* Xh  = (_Float16*)smem;
  _Float16* A_l = (_Float16*)smem;           // phi result [m][s], stride 136
  _Float16* E_l = (_Float16*)(smem + 17408); // e*cm [n][s], stride 136

  int t = threadIdx.x;
  int lane = t & 63, wv = t >> 6, ln = lane & 15, q = lane >> 4;
  int bid = blockIdx.x, b = bid >> 7, chunk = bid & 127;
  int s0 = chunk * 128;

  // ---- stage x tile [128c][128s] fp32 -> fp16 LDS (64KB coalesced reads) ----
  const float* xb = x + (size_t)b*CC*SB + s0;
  #pragma unroll
  for (int r = 0; r < 16; ++r) {
    int fid = r*256 + t;               // 4096 float4-chunks
    int c = fid >> 5, s4 = (fid & 31) << 2;
    float4 v = *(const float4*)(xb + (size_t)c*SB + s4);
    half2_t p0 = { (_Float16)v.x, (_Float16)v.y };
    half2_t p1 = { (_Float16)v.z, (_Float16)v.w };
    *(half2_t*)&Xh[c*138 + s4]     = p0;   // 4B-aligned b32 writes, ~2-way max
    *(half2_t*)&Xh[c*138 + s4 + 2] = p1;
  }
  __syncthreads();

  // ---- B-fragments for this wave's 32 positions (regs, live across all 3 sets) ----
  int myp = wv * 32;
  half8_t bf[2][4];
  #pragma unroll
  for (int nt = 0; nt < 2; ++nt) {
    int s = myp + nt*16 + ln;
    #pragma unroll
    for (int kk = 0; kk < 4; ++kk) {
      half8_t h;
      #pragma unroll
      for (int j = 0; j < 8; ++j) h[j] = Xh[(kk*32 + q*8 + j)*138 + s];
      bf[nt][kk] = h;
    }
  }

  int gsl[2] = { s0 + myp + ln, s0 + myp + 16 + ln };
  float cmv[2] = { cm[b*1024 + (gsl[0] & 1023)], cm[b*1024 + (gsl[1] & 1023)] };
  __syncthreads();                     // all Xh reads done -> A_l/E_l may be written

  half8_t af[4][4];
  f32x4 d[4][2];
  float ev[4][2][4];

  auto conv = [&](int setoff) {
    #pragma unroll
    for (int mt = 0; mt < 4; ++mt)
      #pragma unroll
      for (int kk = 0; kk < 4; ++kk)
        af[mt][kk] = *(const half8_t*)(wh + setoff + (mt*16 + ln)*128 + kk*32 + q*8);
    #pragma unroll
    for (int mt = 0; mt < 4; ++mt)
      #pragma unroll
      for (int nt = 0; nt < 2; ++nt)
        d[mt][nt] = (f32x4){0.f, 0.f, 0.f, 0.f};
    #pragma unroll
    for (int kk = 0; kk < 4; ++kk)
      #pragma unroll
      for (int mt = 0; mt < 4; ++mt)
        #pragma unroll
        for (int nt = 0; nt < 2; ++nt)
          d[mt][nt] = __builtin_amdgcn_mfma_f32_16x16x32_f16(af[mt][kk], bf[nt][kk],
                                                             d[mt][nt], 0, 0, 0);
  };

  // ---- set 0: phi -> A_l[m][s] fp16 ----
  conv(0);
  #pragma unroll
  for (int mt = 0; mt < 4; ++mt) {
    float bv[4]; *(float4*)bv = *(const float4*)(bias + mt*16 + q*4);
    #pragma unroll
    for (int nt = 0; nt < 2; ++nt)
      #pragma unroll
      for (int r = 0; r < 4; ++r)
        A_l[(mt*16 + q*4 + r)*136 + myp + nt*16 + ln] = (_Float16)(d[mt][nt][r] + bv[r]);
  }

  // ---- set 1: theta -> e (EXACT, kept in regs); ec -> E_l; sumE partials ----
  conv(8192);
  float sp[4][4];
  #pragma unroll
  for (int mt = 0; mt < 4; ++mt) {
    float bv[4]; *(float4*)bv = *(const float4*)(bias + 64 + mt*16 + q*4);
    #pragma unroll
    for (int r = 0; r < 4; ++r) {
      #pragma unroll
      for (int nt = 0; nt < 2; ++nt) {
        float e = __expf(d[mt][nt][r] + bv[r]);
        ev[mt][nt][r] = e;
        E_l[(mt*16 + q*4 + r)*136 + myp + nt*16 + ln] = (_Float16)(e * cmv[nt]);
      }
      sp[mt][r] = ev[mt][0][r] + ev[mt][1][r];
    }
  }
  #pragma unroll
  for (int mt = 0; mt < 4; ++mt)
    #pragma unroll
    for (int r = 0; r < 4; ++r) {
      float v = sp[mt][r];
      v += __shfl_xor(v, 1); v += __shfl_xor(v, 2);
      v += __shfl_xor(v, 4); v += __shfl_xor(v, 8);
      sp[mt][r] = v;          // sum over the 16 positions of this n-tile pair
    }
  if (ln == 0) {
    #pragma unroll
    for (int mt = 0; mt < 4; ++mt)
      #pragma unroll
      for (int r = 0; r < 4; ++r)
        se_l[wv*64 + mt*16 + q*4 + r] = sp[mt][r];
  }

  // ---- set 2: rho -> V (channel softmax); V and P = e*V staged to LDS ----
  conv(16384);
  #pragma unroll
  for (int mt = 0; mt < 4; ++mt) {
    float bv[4]; *(float4*)bv = *(const float4*)(bias + 128 + mt*16 + q*4);
    #pragma unroll
    for (int nt = 0; nt < 2; ++nt)
      #pragma unroll
      for (int r = 0; r < 4; ++r)
        d[mt][nt][r] = __expf(d[mt][nt][r] + bv[r]);
  }
  float cs[2] = {0.f, 0.f};
  #pragma unroll
  for (int mt = 0; mt < 4; ++mt)
    #pragma unroll
    for (int nt = 0; nt < 2; ++nt)
      #pragma unroll
      for (int r = 0; r < 4; ++r) cs[nt] += d[mt][nt][r];
  #pragma unroll
  for (int nt = 0; nt < 2; ++nt) {            // sum over 4 quads -> all 64 channels
    cs[nt] += __shfl_xor(cs[nt], 16);
    cs[nt] += __shfl_xor(cs[nt], 32);
    cs[nt] = 1.f / cs[nt];
  }
  #pragma unroll
  for (int nt = 0; nt < 2; ++nt) {
    int srow = myp + nt*16 + ln;
    #pragma unroll
    for (int mt = 0; mt < 4; ++mt) {
      half4_t hv, hp;
      #pragma unroll
      for (int r = 0; r < 4; ++r) {
        float vv = d[mt][nt][r] * cs[nt];
        hv[r] = (_Float16)vv;
        hp[r] = (_Float16)(vv * ev[mt][nt][r]);   // single fp16 rounding of P
      }
      *(half4_t*)&Vst[srow*72 + mt*16 + q*4] = hv;
      *(half4_t*)&Pst[srow*72 + mt*16 + q*4] = hp;
    }
  }
  __syncthreads();                             // A_l, E_l, se_l, Vst, Pst complete

  if (t < 64) {
    float ssum = se_l[t] + se_l[64+t] + se_l[128+t] + se_l[192+t];
    atomicAdd(&sumE[b*64 + t], ssum);
  }

  // ---- AB rank-128 update via MFMA: AB[m][n] += A[m][s] * ec[n][s] ----
  // wave wv -> m-tile wv; atomicAdd into AB f32 (no part buffer, no k2)
  f32x4 dab[4];
  #pragma unroll
  for (int n2 = 0; n2 < 4; ++n2) dab[n2] = (f32x4){0.f, 0.f, 0.f, 0.f};
  #pragma unroll
  for (int kk = 0; kk < 4; ++kk) {
    half8_t aab = *(half8_t*)&A_l[(wv*16 + ln)*136 + kk*32 + q*8];
    #pragma unroll
    for (int n2 = 0; n2 < 4; ++n2) {
      half8_t bab = *(half8_t*)&E_l[(n2*16 + ln)*136 + kk*32 + q*8];
      dab[n2] = __builtin_amdgcn_mfma_f32_16x16x32_f16(aab, bab, dab[n2], 0, 0, 0);
    }
  }
  float* ab = abf + b*4096;
  #pragma unroll
  for (int n2 = 0; n2 < 4; ++n2)
    #pragma unroll
    for (int r = 0; r < 4; ++r)
      atomicAdd(&ab[(wv*16 + q*4 + r)*64 + n2*16 + ln], dab[n2][r]);

  // ---- coalesced flush: Vst/Pst -> vt/pt, 4KB contiguous per wave-instr ----
  {
    _Float16* vg = vt + ((size_t)b*SB + s0)*64;
    char*     pg = ptb + ((size_t)b*SB + s0)*128;
    #pragma unroll
    for (int it = 0; it < 4; ++it) {
      int fid = it*256 + t;            // 1024 chunks of 16B (8 per 128B row)
      int row = fid >> 3, ck = fid & 7;
      *(half8_t*)(vg + row*64 + ck*8) = *(half8_t*)&Vst[row*72 + ck*8];
    }
    #pragma unroll
    for (int it = 0; it < 4; ++it) {
      int fid = it*256 + t;
      int row = fid >> 3, ck = fid & 7;
      *(half8_t*)(pg + (size_t)row*128 + ck*16) = *(half8_t*)&Pst[row*72 + ck*8];
    }
  }
}

// ------------- k34: Z GEMM (blocks 0..511) || attn transpose (blocks 512..1023)
// R14: out stores back to NORMAL (R13's NT stores regressed +7.5us -- out
// WANTS L2 write-combining). Instead, NON-TEMPORAL LOADS on the one-shot
// streaming reads (vt in Z-half, pt in attn-half): these 34MB are read
// exactly once; read-allocate evicts the out write-combining lines from the
// 4MB per-XCD L2. NT loads keep L2 for the store stream. abf/sumE stay
// cached (re-read 64x/batch). Values identical; pure cache-policy hint.
__global__ __launch_bounds__(256) void k34(const float* __restrict__ abf,
                                           const _Float16* __restrict__ vt,
                                           const char* __restrict__ ptb,
                                           const float* __restrict__ sumE,
                                           float* __restrict__ out) {
  __shared__ _Float16 sm[256*72];              // k3 uses first 64*72, k4 all of it
  int t = threadIdx.x;
  if (blockIdx.x < 512) {
    // ---- Z[m][s] = sum_n ABt[m][n] * V[n][s], 8b * 64 chunks(256 s) ----
    _Float16* Ah = sm;                         // [64][72]
    int lane = t & 63, wv = t >> 6, ln = lane & 15, q = lane >> 4;
    int bid = blockIdx.x, b = bid >> 6, chunk = bid & 63;
    int s0 = chunk * 256;
    const float* ab = abf + b*4096;
    const float* se = sumE + b*64;
    #pragma unroll
    for (int r = 0; r < 16; ++r) {
      int idx = r*256 + t;
      int m = idx >> 6, n = idx & 63;
      // x1024: keeps fp16 values well clear of denormals (AB/sumE ~ 2e-4); undone below
      Ah[m*72 + n] = (_Float16)(ab[idx] * (1024.f / se[n]));
    }
    __syncthreads();
    half8_t a8[4][2];
    #pragma unroll
    for (int mt = 0; mt < 4; ++mt)
      #pragma unroll
      for (int kk = 0; kk < 2; ++kk)
        a8[mt][kk] = *(half8_t*)&Ah[(mt*16 + ln)*72 + kk*32 + q*8];
    int sw = s0 + wv*64;
    #pragma unroll
    for (int nt = 0; nt < 4; ++nt) {
      int sb = sw + nt*16 + ln;
      const _Float16* vrow = vt + ((size_t)b*SB + sb)*64;
      half8_t b8[2];
      b8[0] = __builtin_nontemporal_load((const half8_t*)(vrow + q*8));
      b8[1] = __builtin_nontemporal_load((const half8_t*)(vrow + 32 + q*8));
      f32x4 dz[4];
      #pragma unroll
      for (int mt = 0; mt < 4; ++mt) dz[mt] = (f32x4){0.f, 0.f, 0.f, 0.f};
      #pragma unroll
      for (int kk = 0; kk < 2; ++kk)
        #pragma unroll
        for (int mt = 0; mt < 4; ++mt)
          dz[mt] = __builtin_amdgcn_mfma_f32_16x16x32_f16(a8[mt][kk], b8[kk], dz[mt], 0, 0, 0);
      #pragma unroll
      for (int mt = 0; mt < 4; ++mt)
        #pragma unroll
        for (int r = 0; r < 4; ++r)
          out[((size_t)(b*64 + mt*16 + q*4 + r))*SB + sb] = dz[mt][r] * (1.f/1024.f);
    }
  } else {
    // ---- attn[n][hw][t] = P[s][n] / sumE[n]; 8b * 64 hw-blocks(16 hw) ----
    _Float16* P_l = sm;                        // [256][72]
    int bid = blockIdx.x - 512;
    int b = bid >> 6, hw0 = (bid & 63) * 16;
    int st = t >> 4, h = t & 15;
    int s = st*1024 + hw0 + h;
    const char* prow = ptb + ((size_t)b*SB + s)*128;
    #pragma unroll
    for (int c8 = 0; c8 < 8; ++c8)
      *(half8_t*)&P_l[t*72 + c8*8] =
          __builtin_nontemporal_load((const half8_t*)(prow + c8*16));
    __syncthreads();
    int n = t >> 2, oc = t & 3;
    float ri = 1.f / sumE[b*64 + n];
    float* orow = out + 8388608 + (size_t)(b*64 + n)*SB + hw0*16;
    #pragma unroll
    for (int i = 0; i < 16; ++i) {
      int j = i*16 + oc*4;                     // 4-lane oc-groups: 64B contiguous
      float w[4];
      #pragma unroll
      for (int r = 0; r < 4; ++r)
        w[r] = (float)P_l[((oc*4 + r)*16 + i)*72 + n] * ri;
      *(float4*)(orow + j) = *(float4*)w;
    }
  }
}

extern "C" void kernel_launch(void* const* d_in, const int* in_sizes, int n_in,
                              void* d_out, int out_size, void* d_ws, size_t ws_size,
                              hipStream_t stream) {
  const float* input   = (const float*)d_in[0];
  const float* cond    = (const float*)d_in[1];
  const float* W_phi   = (const float*)d_in[2];
  const float* b_phi   = (const float*)d_in[3];
  const float* W_theta = (const float*)d_in[4];
  const float* b_theta = (const float*)d_in[5];
  const float* W_rho   = (const float*)d_in[6];
  const float* b_rho   = (const float*)d_in[7];
  const float* W1      = (const float*)d_in[8];
  const float* b1      = (const float*)d_in[9];
  const float* W2      = (const float*)d_in[10];
  const float* b2      = (const float*)d_in[11];
  char* wsc = (char*)d_ws;
  float* out = (float*)d_out;

  const _Float16* wh = (const _Float16*)(wsc + WH_OFF);
  const float* bias = (const float*)(wsc + BIAS_OFF);
  const float* cmp  = (const float*)(wsc + CM_OFF);
  float* sumE  = (float*)(wsc + SUME_OFF);
  float* abf   = (float*)(wsc + AB_OFF);
  _Float16* vt = (_Float16*)(wsc + VT_OFF);

  hipLaunchKernelGGL(k0_setup, dim3(16), dim3(256), 0, stream,
                     cond, W_phi, b_phi, W_theta, b_theta, W_rho, b_rho,
                     W1, b1, W2, b2, wsc);
  hipLaunchKernelGGL(kC_main, dim3(1024), dim3(256), 0, stream,
                     input, wh, bias, cmp, sumE, vt, (char*)(wsc + PT_OFF), abf);
  hipLaunchKernelGGL(k34, dim3(1024), dim3(256), 0, stream,
                     abf, vt, (const char*)(wsc + PT_OFF), sumE, out);
}

// Round 15
// 185.009 us; speedup vs baseline: 1.0768x; 1.0768x over previous
//
#include <hip/hip_runtime.h>

#define CC 128
#define SB 16384   // T*H*W

typedef _Float16 half2_t __attribute__((ext_vector_type(2)));
typedef _Float16 half4_t __attribute__((ext_vector_type(4)));
typedef _Float16 half8_t __attribute__((ext_vector_type(8)));
typedef float    f32x4  __attribute__((ext_vector_type(4)));

// ---- workspace map ----
#define WH_OFF   0u         // 3*64*128 fp16 weights [set][m][k]
#define BIAS_OFF 49152u     // 192 f32
#define CM_OFF   50176u     // 8*1024 f32 Cm
#define SUME_OFF 82944u     // 512 f32 (zeroed by k0, atomicAdd by kC)
#define AB_OFF   86016u     // 8*4096 f32 AB accumulators (zeroed by k0, atomicAdd by kC)
#define PT_OFF   262144u    // P_t = e*V fp16 [b][s][n0..63], dense 128B rows (16.8MB)
#define VT_OFF   33816576u  // 8*16384*64 fp16 V [s][n]

// ---------------------------------------------------------------- k0: setup
// R10-proven: MLP weight reads vectorized (float4) -- was the G13 violation
// (64 scalar fp32 loads/output at 256B lane stride); -10.3us total.
__global__ void k0_setup(const float* __restrict__ cond,
                         const float* __restrict__ W_phi, const float* __restrict__ b_phi,
                         const float* __restrict__ W_theta, const float* __restrict__ b_theta,
                         const float* __restrict__ W_rho, const float* __restrict__ b_rho,
                         const float* __restrict__ W1, const float* __restrict__ b1,
                         const float* __restrict__ W2, const float* __restrict__ b2,
                         char* __restrict__ wsc) {
  __shared__ float sc[64], sh1[64], red[256];
  int t = threadIdx.x, bid = blockIdx.x;
  if (bid < 8) {
    int b = bid;
    if (t < 64) sc[t] = cond[b*64 + t];
    __syncthreads();
    if (t < 64) {
      float acc = b1[t];
      const float4* w1r = (const float4*)(W1 + t*64);
      #pragma unroll
      for (int k = 0; k < 16; ++k) {
        float4 w = w1r[k];
        acc += sc[k*4+0]*w.x + sc[k*4+1]*w.y + sc[k*4+2]*w.z + sc[k*4+3]*w.w;
      }
      sh1[t] = fmaxf(acc, 0.f);
    }
    __syncthreads();
    float ev[4]; float ps = 0.f;
    #pragma unroll
    for (int q = 0; q < 4; ++q) {
      int o = q*256 + t;
      float acc = b2[o];
      const float4* w2r = (const float4*)(W2 + o*64);
      #pragma unroll
      for (int k = 0; k < 16; ++k) {
        float4 w = w2r[k];
        acc += sh1[k*4+0]*w.x + sh1[k*4+1]*w.y + sh1[k*4+2]*w.z + sh1[k*4+3]*w.w;
      }
      ev[q] = __expf(fmaxf(acc, 0.f));
      ps += ev[q];
    }
    red[t] = ps; __syncthreads();
    for (int s = 128; s > 0; s >>= 1) { if (t < s) red[t] += red[t+s]; __syncthreads(); }
    float inv = 1.f / red[0];
    float* cm = (float*)(wsc + CM_OFF);
    #pragma unroll
    for (int q = 0; q < 4; ++q) cm[b*1024 + q*256 + t] = ev[q] * inv;
  } else {
    int r = bid - 8;
    _Float16* wh = (_Float16*)(wsc + WH_OFF);
    for (int i = r*256 + t; i < 24576; i += 2048) {
      int set = i >> 13, mk = i & 8191;
      const float* W = (set == 0) ? W_phi : (set == 1 ? W_theta : W_rho);
      wh[i] = (_Float16)W[mk];       // all W_* are [64][128] row-major already
    }
    float* ab = (float*)(wsc + AB_OFF);
    for (int i = r*256 + t; i < 32768; i += 2048) ab[i] = 0.f;
    if (r == 0 && t < 192) {
      float* bias = (float*)(wsc + BIAS_OFF);
      bias[t] = (t < 64) ? b_phi[t] : (t < 128 ? b_theta[t-64] : b_rho[t-128]);
    }
    if (r == 1) {
      float* se = (float*)(wsc + SUME_OFF);
      for (int i = t; i < 512; i += 256) se[i] = 0.f;
    }
  }
}

// ------------------------------------- kC: transpose-in-LDS + 3 convs (MFMA)
//                                          + epilogues + AB atomic accumulation
// FROZEN at R12 (54-58us, VGPR 88). Conv body = R6 codegen law (FULL
// af[4][4]+bf[2][4] preload at 128-s tile; all restructures collapsed to
// VGPR<=64 and serialized: R3/R5/R7). Tail = R12 LDS-bounced coalesced flush
// (-5us from halved store-instruction count; WRITE_SIZE unchanged -- L2
// assembles full lines regardless, the +16.8MB over ideal is the AB atomics'
// memory-side RMW traffic, structural to k2-elimination). Do NOT touch.
// ev[4][2][4] f32 MUST stay exact in regs (fp16 e-roundtrip fails attn, R2).
// Frag maps (m89/m120-verified): A[m=ln][k=q*8+j], B[k=q*8+j][n=ln], D[m=q*4+r][n=ln].
__global__ __launch_bounds__(256, 2) void kC_main(
    const float* __restrict__ x, const _Float16* __restrict__ wh,
    const float* __restrict__ bias, const float* __restrict__ cm,
    float* __restrict__ sumE, _Float16* __restrict__ vt,
    char* __restrict__ ptb,            // P region base (dense 128B rows)
    float* __restrict__ abf) {         // [8][64][64] f32 atomic accumulators
  __shared__ char smem[35328];         // union: Xh[128*138] | (A_l[64*136] + E_l[64*136])
  __shared__ float se_l[256];          // per-wave sumE partials [wv][64]
  __shared__ _Float16 Vst[128*72];     // V staging [s][n], 144B rows
  __shared__ _Float16 Pst[128*72];     // P staging [s][n], 144B rows
  _Float16* Xh  = (_Float16*)smem;
  _Float16* A_l = (_Float16*)smem;           // phi result [m][s], stride 136
  _Float16* E_l = (_Float16*)(smem + 17408); // e*cm [n][s], stride 136

  int t = threadIdx.x;
  int lane = t & 63, wv = t >> 6, ln = lane & 15, q = lane >> 4;
  int bid = blockIdx.x, b = bid >> 7, chunk = bid & 127;
  int s0 = chunk * 128;

  // ---- stage x tile [128c][128s] fp32 -> fp16 LDS (64KB coalesced reads) ----
  const float* xb = x + (size_t)b*CC*SB + s0;
  #pragma unroll
  for (int r = 0; r < 16; ++r) {
    int fid = r*256 + t;               // 4096 float4-chunks
    int c = fid >> 5, s4 = (fid & 31) << 2;
    float4 v = *(const float4*)(xb + (size_t)c*SB + s4);
    half2_t p0 = { (_Float16)v.x, (_Float16)v.y };
    half2_t p1 = { (_Float16)v.z, (_Float16)v.w };
    *(half2_t*)&Xh[c*138 + s4]     = p0;   // 4B-aligned b32 writes, ~2-way max
    *(half2_t*)&Xh[c*138 + s4 + 2] = p1;
  }
  __syncthreads();

  // ---- B-fragments for this wave's 32 positions (regs, live across all 3 sets) ----
  int myp = wv * 32;
  half8_t bf[2][4];
  #pragma unroll
  for (int nt = 0; nt < 2; ++nt) {
    int s = myp + nt*16 + ln;
    #pragma unroll
    for (int kk = 0; kk < 4; ++kk) {
      half8_t h;
      #pragma unroll
      for (int j = 0; j < 8; ++j) h[j] = Xh[(kk*32 + q*8 + j)*138 + s];
      bf[nt][kk] = h;
    }
  }

  int gsl[2] = { s0 + myp + ln, s0 + myp + 16 + ln };
  float cmv[2] = { cm[b*1024 + (gsl[0] & 1023)], cm[b*1024 + (gsl[1] & 1023)] };
  __syncthreads();                     // all Xh reads done -> A_l/E_l may be written

  half8_t af[4][4];
  f32x4 d[4][2];
  float ev[4][2][4];

  auto conv = [&](int setoff) {
    #pragma unroll
    for (int mt = 0; mt < 4; ++mt)
      #pragma unroll
      for (int kk = 0; kk < 4; ++kk)
        af[mt][kk] = *(const half8_t*)(wh + setoff + (mt*16 + ln)*128 + kk*32 + q*8);
    #pragma unroll
    for (int mt = 0; mt < 4; ++mt)
      #pragma unroll
      for (int nt = 0; nt < 2; ++nt)
        d[mt][nt] = (f32x4){0.f, 0.f, 0.f, 0.f};
    #pragma unroll
    for (int kk = 0; kk < 4; ++kk)
      #pragma unroll
      for (int mt = 0; mt < 4; ++mt)
        #pragma unroll
        for (int nt = 0; nt < 2; ++nt)
          d[mt][nt] = __builtin_amdgcn_mfma_f32_16x16x32_f16(af[mt][kk], bf[nt][kk],
                                                             d[mt][nt], 0, 0, 0);
  };

  // ---- set 0: phi -> A_l[m][s] fp16 ----
  conv(0);
  #pragma unroll
  for (int mt = 0; mt < 4; ++mt) {
    float bv[4]; *(float4*)bv = *(const float4*)(bias + mt*16 + q*4);
    #pragma unroll
    for (int nt = 0; nt < 2; ++nt)
      #pragma unroll
      for (int r = 0; r < 4; ++r)
        A_l[(mt*16 + q*4 + r)*136 + myp + nt*16 + ln] = (_Float16)(d[mt][nt][r] + bv[r]);
  }

  // ---- set 1: theta -> e (EXACT, kept in regs); ec -> E_l; sumE partials ----
  conv(8192);
  float sp[4][4];
  #pragma unroll
  for (int mt = 0; mt < 4; ++mt) {
    float bv[4]; *(float4*)bv = *(const float4*)(bias + 64 + mt*16 + q*4);
    #pragma unroll
    for (int r = 0; r < 4; ++r) {
      #pragma unroll
      for (int nt = 0; nt < 2; ++nt) {
        float e = __expf(d[mt][nt][r] + bv[r]);
        ev[mt][nt][r] = e;
        E_l[(mt*16 + q*4 + r)*136 + myp + nt*16 + ln] = (_Float16)(e * cmv[nt]);
      }
      sp[mt][r] = ev[mt][0][r] + ev[mt][1][r];
    }
  }
  #pragma unroll
  for (int mt = 0; mt < 4; ++mt)
    #pragma unroll
    for (int r = 0; r < 4; ++r) {
      float v = sp[mt][r];
      v += __shfl_xor(v, 1); v += __shfl_xor(v, 2);
      v += __shfl_xor(v, 4); v += __shfl_xor(v, 8);
      sp[mt][r] = v;          // sum over the 16 positions of this n-tile pair
    }
  if (ln == 0) {
    #pragma unroll
    for (int mt = 0; mt < 4; ++mt)
      #pragma unroll
      for (int r = 0; r < 4; ++r)
        se_l[wv*64 + mt*16 + q*4 + r] = sp[mt][r];
  }

  // ---- set 2: rho -> V (channel softmax); V and P = e*V staged to LDS ----
  conv(16384);
  #pragma unroll
  for (int mt = 0; mt < 4; ++mt) {
    float bv[4]; *(float4*)bv = *(const float4*)(bias + 128 + mt*16 + q*4);
    #pragma unroll
    for (int nt = 0; nt < 2; ++nt)
      #pragma unroll
      for (int r = 0; r < 4; ++r)
        d[mt][nt][r] = __expf(d[mt][nt][r] + bv[r]);
  }
  float cs[2] = {0.f, 0.f};
  #pragma unroll
  for (int mt = 0; mt < 4; ++mt)
    #pragma unroll
    for (int nt = 0; nt < 2; ++nt)
      #pragma unroll
      for (int r = 0; r < 4; ++r) cs[nt] += d[mt][nt][r];
  #pragma unroll
  for (int nt = 0; nt < 2; ++nt) {            // sum over 4 quads -> all 64 channels
    cs[nt] += __shfl_xor(cs[nt], 16);
    cs[nt] += __shfl_xor(cs[nt], 32);
    cs[nt] = 1.f / cs[nt];
  }
  #pragma unroll
  for (int nt = 0; nt < 2; ++nt) {
    int srow = myp + nt*16 + ln;
    #pragma unroll
    for (int mt = 0; mt < 4; ++mt) {
      half4_t hv, hp;
      #pragma unroll
      for (int r = 0; r < 4; ++r) {
        float vv = d[mt][nt][r] * cs[nt];
        hv[r] = (_Float16)vv;
        hp[r] = (_Float16)(vv * ev[mt][nt][r]);   // single fp16 rounding of P
      }
      *(half4_t*)&Vst[srow*72 + mt*16 + q*4] = hv;
      *(half4_t*)&Pst[srow*72 + mt*16 + q*4] = hp;
    }
  }
  __syncthreads();                             // A_l, E_l, se_l, Vst, Pst complete

  if (t < 64) {
    float ssum = se_l[t] + se_l[64+t] + se_l[128+t] + se_l[192+t];
    atomicAdd(&sumE[b*64 + t], ssum);
  }

  // ---- AB rank-128 update via MFMA: AB[m][n] += A[m][s] * ec[n][s] ----
  // wave wv -> m-tile wv; atomicAdd into AB f32 (no part buffer, no k2)
  f32x4 dab[4];
  #pragma unroll
  for (int n2 = 0; n2 < 4; ++n2) dab[n2] = (f32x4){0.f, 0.f, 0.f, 0.f};
  #pragma unroll
  for (int kk = 0; kk < 4; ++kk) {
    half8_t aab = *(half8_t*)&A_l[(wv*16 + ln)*136 + kk*32 + q*8];
    #pragma unroll
    for (int n2 = 0; n2 < 4; ++n2) {
      half8_t bab = *(half8_t*)&E_l[(n2*16 + ln)*136 + kk*32 + q*8];
      dab[n2] = __builtin_amdgcn_mfma_f32_16x16x32_f16(aab, bab, dab[n2], 0, 0, 0);
    }
  }
  float* ab = abf + b*4096;
  #pragma unroll
  for (int n2 = 0; n2 < 4; ++n2)
    #pragma unroll
    for (int r = 0; r < 4; ++r)
      atomicAdd(&ab[(wv*16 + q*4 + r)*64 + n2*16 + ln], dab[n2][r]);

  // ---- coalesced flush: Vst/Pst -> vt/pt, 4KB contiguous per wave-instr ----
  {
    _Float16* vg = vt + ((size_t)b*SB + s0)*64;
    char*     pg = ptb + ((size_t)b*SB + s0)*128;
    #pragma unroll
    for (int it = 0; it < 4; ++it) {
      int fid = it*256 + t;            // 1024 chunks of 16B (8 per 128B row)
      int row = fid >> 3, ck = fid & 7;
      *(half8_t*)(vg + row*64 + ck*8) = *(half8_t*)&Vst[row*72 + ck*8];
    }
    #pragma unroll
    for (int it = 0; it < 4; ++it) {
      int fid = it*256 + t;
      int row = fid >> 3, ck = fid & 7;
      *(half8_t*)(pg + (size_t)row*128 + ck*16) = *(half8_t*)&Pst[row*72 + ck*8];
    }
  }
}

// ------------- k34: Z GEMM (blocks 0..511) || attn transpose (blocks 512..1023)
// FINAL = R12 configuration. R11's 64B-contiguous attn store remap (-5.8us).
// Cache policy: DEFAULT on all loads and stores -- R13 (NT stores, +7.5us)
// and R14 (NT loads, +12us) both proved the L2's write-combining and
// read-allocate behavior is already optimal for these streams.
__global__ __launch_bounds__(256) void k34(const float* __restrict__ abf,
                                           const _Float16* __restrict__ vt,
                                           const char* __restrict__ ptb,
                                           const float* __restrict__ sumE,
                                           float* __restrict__ out) {
  __shared__ _Float16 sm[256*72];              // k3 uses first 64*72, k4 all of it
  int t = threadIdx.x;
  if (blockIdx.x < 512) {
    // ---- Z[m][s] = sum_n ABt[m][n] * V[n][s], 8b * 64 chunks(256 s) ----
    _Float16* Ah = sm;                         // [64][72]
    int lane = t & 63, wv = t >> 6, ln = lane & 15, q = lane >> 4;
    int bid = blockIdx.x, b = bid >> 6, chunk = bid & 63;
    int s0 = chunk * 256;
    const float* ab = abf + b*4096;
    const float* se = sumE + b*64;
    #pragma unroll
    for (int r = 0; r < 16; ++r) {
      int idx = r*256 + t;
      int m = idx >> 6, n = idx & 63;
      // x1024: keeps fp16 values well clear of denormals (AB/sumE ~ 2e-4); undone below
      Ah[m*72 + n] = (_Float16)(ab[idx] * (1024.f / se[n]));
    }
    __syncthreads();
    half8_t a8[4][2];
    #pragma unroll
    for (int mt = 0; mt < 4; ++mt)
      #pragma unroll
      for (int kk = 0; kk < 2; ++kk)
        a8[mt][kk] = *(half8_t*)&Ah[(mt*16 + ln)*72 + kk*32 + q*8];
    int sw = s0 + wv*64;
    #pragma unroll
    for (int nt = 0; nt < 4; ++nt) {
      int sb = sw + nt*16 + ln;
      const _Float16* vrow = vt + ((size_t)b*SB + sb)*64;
      half8_t b8[2];
      b8[0] = *(const half8_t*)(vrow + q*8);
      b8[1] = *(const half8_t*)(vrow + 32 + q*8);
      f32x4 dz[4];
      #pragma unroll
      for (int mt = 0; mt < 4; ++mt) dz[mt] = (f32x4){0.f, 0.f, 0.f, 0.f};
      #pragma unroll
      for (int kk = 0; kk < 2; ++kk)
        #pragma unroll
        for (int mt = 0; mt < 4; ++mt)
          dz[mt] = __builtin_amdgcn_mfma_f32_16x16x32_f16(a8[mt][kk], b8[kk], dz[mt], 0, 0, 0);
      #pragma unroll
      for (int mt = 0; mt < 4; ++mt)
        #pragma unroll
        for (int r = 0; r < 4; ++r)
          out[((size_t)(b*64 + mt*16 + q*4 + r))*SB + sb] = dz[mt][r] * (1.f/1024.f);
    }
  } else {
    // ---- attn[n][hw][t] = P[s][n] / sumE[n]; 8b * 64 hw-blocks(16 hw) ----
    _Float16* P_l = sm;                        // [256][72]
    int bid = blockIdx.x - 512;
    int b = bid >> 6, hw0 = (bid & 63) * 16;
    int st = t >> 4, h = t & 15;
    int s = st*1024 + hw0 + h;
    const char* prow = ptb + ((size_t)b*SB + s)*128;
    #pragma unroll
    for (int c8 = 0; c8 < 8; ++c8)
      *(half8_t*)&P_l[t*72 + c8*8] = *(const half8_t*)(prow + c8*16);
    __syncthreads();
    int n = t >> 2, oc = t & 3;
    float ri = 1.f / sumE[b*64 + n];
    float* orow = out + 8388608 + (size_t)(b*64 + n)*SB + hw0*16;
    #pragma unroll
    for (int i = 0; i < 16; ++i) {
      int j = i*16 + oc*4;                     // 4-lane oc-groups: 64B contiguous
      float w[4];
      #pragma unroll
      for (int r = 0; r < 4; ++r)
        w[r] = (float)P_l[((oc*4 + r)*16 + i)*72 + n] * ri;
      *(float4*)(orow + j) = *(float4*)w;
    }
  }
}

extern "C" void kernel_launch(void* const* d_in, const int* in_sizes, int n_in,
                              void* d_out, int out_size, void* d_ws, size_t ws_size,
                              hipStream_t stream) {
  const float* input   = (const float*)d_in[0];
  const float* cond    = (const float*)d_in[1];
  const float* W_phi   = (const float*)d_in[2];
  const float* b_phi   = (const float*)d_in[3];
  const float* W_theta = (const float*)d_in[4];
  const float* b_theta = (const float*)d_in[5];
  const float* W_rho   = (const float*)d_in[6];
  const float* b_rho   = (const float*)d_in[7];
  const float* W1      = (const float*)d_in[8];
  const float* b1      = (const float*)d_in[9];
  const float* W2      = (const float*)d_in[10];
  const float* b2      = (const float*)d_in[11];
  char* wsc = (char*)d_ws;
  float* out = (float*)d_out;

  const _Float16* wh = (const _Float16*)(wsc + WH_OFF);
  const float* bias = (const float*)(wsc + BIAS_OFF);
  const float* cmp  = (const float*)(wsc + CM_OFF);
  float* sumE  = (float*)(wsc + SUME_OFF);
  float* abf   = (float*)(wsc + AB_OFF);
  _Float16* vt = (_Float16*)(wsc + VT_OFF);

  hipLaunchKernelGGL(k0_setup, dim3(16), dim3(256), 0, stream,
                     cond, W_phi, b_phi, W_theta, b_theta, W_rho, b_rho,
                     W1, b1, W2, b2, wsc);
  hipLaunchKernelGGL(kC_main, dim3(1024), dim3(256), 0, stream,
                     input, wh, bias, cmp, sumE, vt, (char*)(wsc + PT_OFF), abf);
  hipLaunchKernelGGL(k34, dim3(1024), dim3(256), 0, stream,
                     abf, vt, (const char*)(wsc + PT_OFF), sumE, out);
}